// Round 1
// baseline (559.710 us; speedup 1.0000x reference)
//
#include <hip/hip_runtime.h>
#include <cstdint>

#define N_NODES 100000
#define N_EDGES 3200000

// ---------------------------------------------------------------------------
// Kernel 0: runtime dtype detection (no host sync allowed under graph capture)
//  flags[0] = 1 if edge_index is int64 (all odd 32-bit words zero), else 0
//  flags[1] = 1 if mask is 1-byte bool (some byte at pos%4!=0 nonzero), else 0
// ---------------------------------------------------------------------------
__global__ void detect_kernel(const uint32_t* __restrict__ ei_words,
                              const uint8_t* __restrict__ mask_bytes,
                              int* __restrict__ flags) {
    __shared__ int s_oddnz, s_bnz;
    if (threadIdx.x == 0) { s_oddnz = 0; s_bnz = 0; }
    __syncthreads();
    int oddnz = 0, bnz = 0;
    // 65536 words (256KB) is safely within edge_index (>=25.6MB) either way.
    // 65536 bytes is safely within mask (>=600000 bytes) either way.
    for (int w = threadIdx.x; w < 65536; w += blockDim.x) {
        if ((w & 1) && ei_words[w] != 0u) oddnz = 1;
        if ((w & 3) && mask_bytes[w] != 0) bnz = 1;
    }
    if (oddnz) s_oddnz = 1;   // race-benign
    if (bnz)   s_bnz = 1;
    __syncthreads();
    if (threadIdx.x == 0) {
        flags[0] = s_oddnz ? 0 : 1;   // no nonzero odd word -> int64
        flags[1] = s_bnz ? 1 : 0;     // nonzero off-aligned byte -> uint8 bool
    }
}

// ---------------------------------------------------------------------------
// Kernel 1: per-node prep. masked select, pack (vm,va) and (pg-pd, qg-qd),
// zero the atomic accumulators and the output.
// ---------------------------------------------------------------------------
__global__ void prep_kernel(const float* __restrict__ pred,
                            const float* __restrict__ target,
                            const void* __restrict__ mask,
                            const int* __restrict__ flags,
                            float2* __restrict__ vmva,
                            float2* __restrict__ base_pq,
                            float2* __restrict__ calc_pq,
                            float* __restrict__ d_out, int out_size) {
    int i = blockIdx.x * blockDim.x + threadIdx.x;
    if (i == 0) {
        for (int k = 0; k < out_size; ++k) d_out[k] = 0.0f;
    }
    if (i >= N_NODES) return;

    const float* pr = pred + (size_t)i * 6;
    const float* tg = target + (size_t)i * 6;
    float tp[6];
    if (flags[1]) {  // 1-byte bool mask
        const uint8_t* mk = (const uint8_t*)mask + (size_t)i * 6;
        #pragma unroll
        for (int j = 0; j < 6; ++j) tp[j] = mk[j] ? pr[j] : tg[j];
    } else {         // int32 mask
        const int* mk = (const int*)mask + (size_t)i * 6;
        #pragma unroll
        for (int j = 0; j < 6; ++j) tp[j] = mk[j] ? pr[j] : tg[j];
    }
    vmva[i]    = make_float2(tp[0], tp[1]);            // vm, va
    base_pq[i] = make_float2(tp[2] - tp[4], tp[3] - tp[5]);  // pg-pd, qg-qd
    calc_pq[i] = make_float2(0.0f, 0.0f);
}

// ---------------------------------------------------------------------------
// Kernel 2: per-edge flow + scatter-add (segment_sum by src).
// ---------------------------------------------------------------------------
__global__ __launch_bounds__(256)
void edge_kernel(const void* __restrict__ edge_index,
                 const float2* __restrict__ edge_attr,
                 const int* __restrict__ flags,
                 const float2* __restrict__ vmva,
                 float2* __restrict__ calc_pq) {
    int e = blockIdx.x * blockDim.x + threadIdx.x;
    if (e >= N_EDGES) return;

    int src, dst;
    if (flags[0]) {  // int64 indices
        const long long* ei = (const long long*)edge_index;
        src = (int)ei[e];
        dst = (int)ei[(size_t)N_EDGES + e];
    } else {         // int32 indices
        const int* ei = (const int*)edge_index;
        src = ei[e];
        dst = ei[(size_t)N_EDGES + e];
    }

    float2 gb = edge_attr[e];      // g, b
    float2 fa = vmva[src];         // vm[src], va[src]
    float2 fb = vmva[dst];         // vm[dst], va[dst]

    float ang = fa.y - fb.y;
    float s, c;
    sincosf(ang, &s, &c);
    float vv = fa.x * fb.x;
    float pf = vv * (gb.x * c + gb.y * s);
    float qf = vv * (gb.x * s - gb.y * c);

    atomicAdd(&calc_pq[src].x, pf);
    atomicAdd(&calc_pq[src].y, qf);
}

// ---------------------------------------------------------------------------
// Kernel 3: per-node squared imbalance -> mean reduction into d_out[0].
// ---------------------------------------------------------------------------
__global__ void finalize_kernel(const float2* __restrict__ base_pq,
                                const float2* __restrict__ calc_pq,
                                float* __restrict__ d_out) {
    int i = blockIdx.x * blockDim.x + threadIdx.x;
    float v = 0.0f;
    if (i < N_NODES) {
        float2 b = base_pq[i], c = calc_pq[i];
        float pi = b.x - c.x;
        float qi = b.y - c.y;
        v = pi * pi + qi * qi;
    }
    // wave64 butterfly reduce
    #pragma unroll
    for (int off = 32; off > 0; off >>= 1) v += __shfl_down(v, off, 64);

    __shared__ float s_part[4];
    int lane = threadIdx.x & 63, wid = threadIdx.x >> 6;
    if (lane == 0) s_part[wid] = v;
    __syncthreads();
    if (threadIdx.x == 0) {
        float t = s_part[0] + s_part[1] + s_part[2] + s_part[3];
        atomicAdd(d_out, t * (1.0f / (float)N_NODES));
    }
}

// ---------------------------------------------------------------------------
extern "C" void kernel_launch(void* const* d_in, const int* in_sizes, int n_in,
                              void* d_out, int out_size, void* d_ws, size_t ws_size,
                              hipStream_t stream) {
    const float*  pred       = (const float*)d_in[0];
    const float*  target     = (const float*)d_in[1];
    const void*   edge_index = d_in[2];
    const float2* edge_attr  = (const float2*)d_in[3];
    const void*   mask       = d_in[4];
    float* out = (float*)d_out;

    char* ws = (char*)d_ws;
    int*    flags   = (int*)ws;                         // 16 B
    float2* vmva    = (float2*)(ws + 1024);             // 800 KB
    float2* base_pq = vmva + N_NODES;                   // 800 KB
    float2* calc_pq = base_pq + N_NODES;                // 800 KB

    detect_kernel<<<1, 256, 0, stream>>>(
        (const uint32_t*)edge_index, (const uint8_t*)mask, flags);

    prep_kernel<<<(N_NODES + 255) / 256, 256, 0, stream>>>(
        pred, target, mask, flags, vmva, base_pq, calc_pq, out, out_size);

    edge_kernel<<<(N_EDGES + 255) / 256, 256, 0, stream>>>(
        edge_index, edge_attr, flags, vmva, calc_pq);

    finalize_kernel<<<(N_NODES + 255) / 256, 256, 0, stream>>>(
        base_pq, calc_pq, out);
}

// Round 3
// 412.986 us; speedup vs baseline: 1.3553x; 1.3553x over previous
//
#include <hip/hip_runtime.h>
#include <cstdint>

#define N_NODES 100000
#define N_EDGES 3200000
#define N_XCD 8

// ---------------------------------------------------------------------------
// Kernel 0: runtime dtype detection + output zeroing.
//  flags[0] = 1 if edge_index is int64 (all sampled odd 32-bit words zero)
//  flags[1] = 1 if mask is 1-byte bool (some sampled byte at pos%4!=0 nonzero)
// 1 block x 1024 threads, 4K words + 8K bytes sampled -> ~2-3 us.
// ---------------------------------------------------------------------------
__global__ __launch_bounds__(1024)
void detect_kernel(const uint32_t* __restrict__ ei_words,
                   const uint8_t* __restrict__ mask_bytes,
                   int* __restrict__ flags,
                   float* __restrict__ d_out, int out_size) {
    __shared__ int s_oddnz, s_bnz;
    if (threadIdx.x == 0) {
        s_oddnz = 0; s_bnz = 0;
        for (int k = 0; k < out_size; ++k) d_out[k] = 0.0f;
    }
    __syncthreads();
    int oddnz = 0, bnz = 0;
    #pragma unroll
    for (int r = 0; r < 4; ++r) {
        int w = r * 1024 + threadIdx.x;           // words [0, 4096)
        if ((w & 1) && ei_words[w] != 0u) oddnz = 1;
        int b0 = r * 2048 + threadIdx.x * 2;      // bytes [0, 8192)
        if ((b0 & 3) && mask_bytes[b0] != 0) bnz = 1;
        if (((b0 + 1) & 3) && mask_bytes[b0 + 1] != 0) bnz = 1;
    }
    if (oddnz) s_oddnz = 1;   // race-benign
    if (bnz)   s_bnz = 1;
    __syncthreads();
    if (threadIdx.x == 0) {
        flags[0] = s_oddnz ? 0 : 1;   // no nonzero odd word -> int64
        flags[1] = s_bnz ? 1 : 0;     // nonzero off-aligned byte -> uint8 bool
    }
}

// ---------------------------------------------------------------------------
// Kernel 1: per-node prep. masked select, pack (vm,va) and (pg-pd, qg-qd),
// zero the 8 per-XCD atomic accumulator replicas.
// ---------------------------------------------------------------------------
__global__ __launch_bounds__(256)
void prep_kernel(const float* __restrict__ pred,
                 const float* __restrict__ target,
                 const void* __restrict__ mask,
                 const int* __restrict__ flags,
                 float2* __restrict__ vmva,
                 float2* __restrict__ base_pq,
                 float2* __restrict__ calc_pq) {
    int i = blockIdx.x * blockDim.x + threadIdx.x;
    if (i >= N_NODES) return;

    const float* pr = pred + (size_t)i * 6;
    const float* tg = target + (size_t)i * 6;
    float tp[6];
    if (flags[1]) {  // 1-byte bool mask
        const uint8_t* mk = (const uint8_t*)mask + (size_t)i * 6;
        #pragma unroll
        for (int j = 0; j < 6; ++j) tp[j] = mk[j] ? pr[j] : tg[j];
    } else {         // int32 mask
        const int* mk = (const int*)mask + (size_t)i * 6;
        #pragma unroll
        for (int j = 0; j < 6; ++j) tp[j] = mk[j] ? pr[j] : tg[j];
    }
    vmva[i]    = make_float2(tp[0], tp[1]);                  // vm, va
    base_pq[i] = make_float2(tp[2] - tp[4], tp[3] - tp[5]);  // pg-pd, qg-qd
    #pragma unroll
    for (int r = 0; r < N_XCD; ++r)
        calc_pq[(size_t)r * N_NODES + i] = make_float2(0.0f, 0.0f);
}

// ---------------------------------------------------------------------------
// Kernel 2: per-edge flow + scatter-add into the replica of THIS wave's XCD.
// Plain global_atomic_add_f32 (no sc0/sc1) = RMW at this XCD's own L2 —
// never leaves the chiplet. All writers of replica i run on XCD i, so
// cross-XCD L2 non-coherence is harmless; end-of-kernel release flushes L2.
// ---------------------------------------------------------------------------
__global__ __launch_bounds__(256)
void edge_kernel(const void* __restrict__ edge_index,
                 const float2* __restrict__ edge_attr,
                 const int* __restrict__ flags,
                 const float2* __restrict__ vmva,
                 float2* __restrict__ calc_pq) {
    int xcc;
    asm volatile("s_getreg_b32 %0, hwreg(HW_REG_XCC_ID)" : "=s"(xcc));
    xcc &= (N_XCD - 1);
    float2* rep = calc_pq + (size_t)xcc * N_NODES;

    int e = blockIdx.x * blockDim.x + threadIdx.x;
    if (e >= N_EDGES) return;

    int src, dst;
    if (flags[0]) {  // int64 indices
        const long long* ei = (const long long*)edge_index;
        src = (int)ei[e];
        dst = (int)ei[(size_t)N_EDGES + e];
    } else {         // int32 indices
        const int* ei = (const int*)edge_index;
        src = ei[e];
        dst = ei[(size_t)N_EDGES + e];
    }

    float2 gb = edge_attr[e];      // g, b
    float2 fa = vmva[src];         // vm[src], va[src]
    float2 fb = vmva[dst];         // vm[dst], va[dst]

    float ang = fa.y - fb.y;
    float s, c;
    sincosf(ang, &s, &c);
    float vv = fa.x * fb.x;
    float pf = vv * (gb.x * c + gb.y * s);
    float qf = vv * (gb.x * s - gb.y * c);

    float* addr = &rep[src].x;
    asm volatile("global_atomic_add_f32 %0, %1, off"
                 :: "v"(addr), "v"(pf) : "memory");
    asm volatile("global_atomic_add_f32 %0, %1, off offset:4"
                 :: "v"(addr), "v"(qf) : "memory");
}

// ---------------------------------------------------------------------------
// Kernel 3: per-node: sum the 8 replicas, squared imbalance -> mean into d_out.
// ---------------------------------------------------------------------------
__global__ __launch_bounds__(256)
void finalize_kernel(const float2* __restrict__ base_pq,
                     const float2* __restrict__ calc_pq,
                     float* __restrict__ d_out) {
    int i = blockIdx.x * blockDim.x + threadIdx.x;
    float v = 0.0f;
    if (i < N_NODES) {
        float cp = 0.0f, cq = 0.0f;
        #pragma unroll
        for (int r = 0; r < N_XCD; ++r) {
            float2 t = calc_pq[(size_t)r * N_NODES + i];
            cp += t.x; cq += t.y;
        }
        float2 b = base_pq[i];
        float pi = b.x - cp;
        float qi = b.y - cq;
        v = pi * pi + qi * qi;
    }
    // wave64 butterfly reduce
    #pragma unroll
    for (int off = 32; off > 0; off >>= 1) v += __shfl_down(v, off, 64);

    __shared__ float s_part[4];
    int lane = threadIdx.x & 63, wid = threadIdx.x >> 6;
    if (lane == 0) s_part[wid] = v;
    __syncthreads();
    if (threadIdx.x == 0) {
        float t = s_part[0] + s_part[1] + s_part[2] + s_part[3];
        atomicAdd(d_out, t * (1.0f / (float)N_NODES));
    }
}

// ---------------------------------------------------------------------------
extern "C" void kernel_launch(void* const* d_in, const int* in_sizes, int n_in,
                              void* d_out, int out_size, void* d_ws, size_t ws_size,
                              hipStream_t stream) {
    const float*  pred       = (const float*)d_in[0];
    const float*  target     = (const float*)d_in[1];
    const void*   edge_index = d_in[2];
    const float2* edge_attr  = (const float2*)d_in[3];
    const void*   mask       = d_in[4];
    float* out = (float*)d_out;

    char* ws = (char*)d_ws;
    int*    flags   = (int*)ws;                         // 16 B
    float2* vmva    = (float2*)(ws + 1024);             // 800 KB
    float2* base_pq = vmva + N_NODES;                   // 800 KB
    float2* calc_pq = base_pq + N_NODES;                // 8 x 800 KB replicas

    detect_kernel<<<1, 1024, 0, stream>>>(
        (const uint32_t*)edge_index, (const uint8_t*)mask, flags, out, out_size);

    prep_kernel<<<(N_NODES + 255) / 256, 256, 0, stream>>>(
        pred, target, mask, flags, vmva, base_pq, calc_pq);

    edge_kernel<<<(N_EDGES + 255) / 256, 256, 0, stream>>>(
        edge_index, edge_attr, flags, vmva, calc_pq);

    finalize_kernel<<<(N_NODES + 255) / 256, 256, 0, stream>>>(
        base_pq, calc_pq, out);
}

// Round 4
// 246.923 us; speedup vs baseline: 2.2667x; 1.6725x over previous
//
#include <hip/hip_runtime.h>
#include <cstdint>

#define N_NODES 100000
#define N_EDGES 3200000

// Fixed-point scale for the packed u64 atomic trick: p,q quantized to
// round(x*4096) int32, packed as (P<<32)+Q. Modular u64 addition keeps the
// fields exact while |sum_field| < 2^31 (actual |sum| < ~2e6). Quantization
// error <= 1.2e-4 per edge, ~64 edges/node -> negligible vs threshold 1.35.
#define FP_SCALE 4096.0f
#define FP_INV   (1.0f / 4096.0f)

// ---------------------------------------------------------------------------
// Kernel 0: runtime dtype detection + output zeroing.
//  flags[0] = 1 if edge_index is int64 (all sampled odd 32-bit words zero)
//  flags[1] = 1 if mask is 1-byte bool (some sampled byte at pos%4!=0 nonzero)
// ---------------------------------------------------------------------------
__global__ __launch_bounds__(1024)
void detect_kernel(const uint32_t* __restrict__ ei_words,
                   const uint8_t* __restrict__ mask_bytes,
                   int* __restrict__ flags,
                   float* __restrict__ d_out, int out_size) {
    __shared__ int s_oddnz, s_bnz;
    if (threadIdx.x == 0) {
        s_oddnz = 0; s_bnz = 0;
        for (int k = 0; k < out_size; ++k) d_out[k] = 0.0f;
    }
    __syncthreads();
    int oddnz = 0, bnz = 0;
    #pragma unroll
    for (int r = 0; r < 4; ++r) {
        int w = r * 1024 + threadIdx.x;           // words [0, 4096)
        if ((w & 1) && ei_words[w] != 0u) oddnz = 1;
        int b0 = r * 2048 + threadIdx.x * 2;      // bytes [0, 8192)
        if ((b0 & 3) && mask_bytes[b0] != 0) bnz = 1;
        if (((b0 + 1) & 3) && mask_bytes[b0 + 1] != 0) bnz = 1;
    }
    if (oddnz) s_oddnz = 1;   // race-benign
    if (bnz)   s_bnz = 1;
    __syncthreads();
    if (threadIdx.x == 0) {
        flags[0] = s_oddnz ? 0 : 1;   // no nonzero odd word -> int64
        flags[1] = s_bnz ? 1 : 0;     // nonzero off-aligned byte -> uint8 bool
    }
}

// ---------------------------------------------------------------------------
// Kernel 1: per-node prep. masked select, pack (vm,va) and (pg-pd, qg-qd),
// zero the packed-u64 accumulator.
// ---------------------------------------------------------------------------
__global__ __launch_bounds__(256)
void prep_kernel(const float* __restrict__ pred,
                 const float* __restrict__ target,
                 const void* __restrict__ mask,
                 const int* __restrict__ flags,
                 float2* __restrict__ vmva,
                 float2* __restrict__ base_pq,
                 unsigned long long* __restrict__ calc_pq) {
    int i = blockIdx.x * blockDim.x + threadIdx.x;
    if (i >= N_NODES) return;

    const float* pr = pred + (size_t)i * 6;
    const float* tg = target + (size_t)i * 6;
    float tp[6];
    if (flags[1]) {  // 1-byte bool mask
        const uint8_t* mk = (const uint8_t*)mask + (size_t)i * 6;
        #pragma unroll
        for (int j = 0; j < 6; ++j) tp[j] = mk[j] ? pr[j] : tg[j];
    } else {         // int32 mask
        const int* mk = (const int*)mask + (size_t)i * 6;
        #pragma unroll
        for (int j = 0; j < 6; ++j) tp[j] = mk[j] ? pr[j] : tg[j];
    }
    vmva[i]    = make_float2(tp[0], tp[1]);                  // vm, va
    base_pq[i] = make_float2(tp[2] - tp[4], tp[3] - tp[5]);  // pg-pd, qg-qd
    calc_pq[i] = 0ull;
}

// ---------------------------------------------------------------------------
// Kernel 2: per-edge flow; ONE u64 atomic per edge carrying both p and q as
// packed int32 fixed-point. Halves atomic transactions vs 2x f32.
// ---------------------------------------------------------------------------
__global__ __launch_bounds__(256)
void edge_kernel(const void* __restrict__ edge_index,
                 const float2* __restrict__ edge_attr,
                 const int* __restrict__ flags,
                 const float2* __restrict__ vmva,
                 unsigned long long* __restrict__ calc_pq) {
    int e = blockIdx.x * blockDim.x + threadIdx.x;
    if (e >= N_EDGES) return;

    int src, dst;
    if (flags[0]) {  // int64 indices
        const long long* ei = (const long long*)edge_index;
        src = (int)ei[e];
        dst = (int)ei[(size_t)N_EDGES + e];
    } else {         // int32 indices
        const int* ei = (const int*)edge_index;
        src = ei[e];
        dst = ei[(size_t)N_EDGES + e];
    }

    float2 gb = edge_attr[e];      // g, b
    float2 fa = vmva[src];         // vm[src], va[src]
    float2 fb = vmva[dst];         // vm[dst], va[dst]

    float ang = fa.y - fb.y;
    float s, c;
    sincosf(ang, &s, &c);
    float vv = fa.x * fb.x;
    float pf = vv * (gb.x * c + gb.y * s);
    float qf = vv * (gb.x * s - gb.y * c);

    int pi = __float2int_rn(pf * FP_SCALE);
    int qi = __float2int_rn(qf * FP_SCALE);
    unsigned long long enc =
        ((unsigned long long)(long long)pi << 32) +
        (unsigned long long)(unsigned int)qi;

    atomicAdd(&calc_pq[src], enc);
}

// ---------------------------------------------------------------------------
// Kernel 3: decode packed sums, squared imbalance -> mean into d_out[0].
// ---------------------------------------------------------------------------
__global__ __launch_bounds__(256)
void finalize_kernel(const float2* __restrict__ base_pq,
                     const unsigned long long* __restrict__ calc_pq,
                     float* __restrict__ d_out) {
    int i = blockIdx.x * blockDim.x + threadIdx.x;
    float v = 0.0f;
    if (i < N_NODES) {
        unsigned long long u = calc_pq[i];
        int   qsum = (int)(unsigned int)(u & 0xFFFFFFFFull);
        long long rem = (long long)(u - (unsigned long long)(long long)qsum);
        int   psum = (int)(rem >> 32);
        float cp = (float)psum * FP_INV;
        float cq = (float)qsum * FP_INV;
        float2 b = base_pq[i];
        float pi = b.x - cp;
        float qi = b.y - cq;
        v = pi * pi + qi * qi;
    }
    // wave64 butterfly reduce
    #pragma unroll
    for (int off = 32; off > 0; off >>= 1) v += __shfl_down(v, off, 64);

    __shared__ float s_part[4];
    int lane = threadIdx.x & 63, wid = threadIdx.x >> 6;
    if (lane == 0) s_part[wid] = v;
    __syncthreads();
    if (threadIdx.x == 0) {
        float t = s_part[0] + s_part[1] + s_part[2] + s_part[3];
        atomicAdd(d_out, t * (1.0f / (float)N_NODES));
    }
}

// ---------------------------------------------------------------------------
extern "C" void kernel_launch(void* const* d_in, const int* in_sizes, int n_in,
                              void* d_out, int out_size, void* d_ws, size_t ws_size,
                              hipStream_t stream) {
    const float*  pred       = (const float*)d_in[0];
    const float*  target     = (const float*)d_in[1];
    const void*   edge_index = d_in[2];
    const float2* edge_attr  = (const float2*)d_in[3];
    const void*   mask       = d_in[4];
    float* out = (float*)d_out;

    char* ws = (char*)d_ws;
    int*                flags   = (int*)ws;                 // 16 B
    float2*             vmva    = (float2*)(ws + 1024);     // 800 KB
    float2*             base_pq = vmva + N_NODES;           // 800 KB
    unsigned long long* calc_pq = (unsigned long long*)(base_pq + N_NODES); // 800 KB

    detect_kernel<<<1, 1024, 0, stream>>>(
        (const uint32_t*)edge_index, (const uint8_t*)mask, flags, out, out_size);

    prep_kernel<<<(N_NODES + 255) / 256, 256, 0, stream>>>(
        pred, target, mask, flags, vmva, base_pq, calc_pq);

    edge_kernel<<<(N_EDGES + 255) / 256, 256, 0, stream>>>(
        edge_index, edge_attr, flags, vmva, calc_pq);

    finalize_kernel<<<(N_NODES + 255) / 256, 256, 0, stream>>>(
        base_pq, calc_pq, out);
}

// Round 5
// 225.353 us; speedup vs baseline: 2.4837x; 1.0957x over previous
//
#include <hip/hip_runtime.h>
#include <cstdint>

#define N_NODES 100000
#define N_EDGES 3200000
#define SPAN    256                              // nodes per bucket
#define SHIFT   8
#define NB      ((N_NODES + SPAN - 1) / SPAN)    // 391 buckets
#define CHUNK   10240                            // edges per bin block
#define NBLK_A  ((N_EDGES + CHUNK - 1) / CHUNK)  // 313 blocks
#define K_MAX   12288                            // bucket capacity cap (mean 8184)

// u64 fixed-point overflow fallback (proven exact in round 4)
#define FP_SCALE 4096.0f
#define FP_INV   (1.0f / 4096.0f)

// ---------------------------------------------------------------------------
// Kernel 1: per-node prep. Inline mask-dtype detect (wave-0 ballot over first
// 64 words: for u8-bool mask some byte at pos%4!=0 is nonzero; for int32 mask
// bytes 1..3 of every word are zero). Computes u = vm*(cos va, sin va),
// base = (pg-pd, qg-qd); zeroes overflow acc, bucket cursors, d_out.
// ---------------------------------------------------------------------------
__global__ __launch_bounds__(256)
void prep_kernel(const float* __restrict__ pred,
                 const float* __restrict__ target,
                 const void* __restrict__ mask,
                 float2* __restrict__ u_tab,
                 float2* __restrict__ base_pq,
                 unsigned long long* __restrict__ ovf,
                 uint32_t* __restrict__ gcursor,
                 float* __restrict__ d_out, int out_size) {
    __shared__ int s_mask8;
    if (threadIdx.x < 64) {
        uint32_t w = ((const uint32_t*)mask)[threadIdx.x];
        bool nz = (w & 0xFFFFFF00u) != 0u;           // any off-aligned byte set
        unsigned long long m = __ballot(nz);
        if (threadIdx.x == 0) s_mask8 = (m != 0ull) ? 1 : 0;
    }
    if (blockIdx.x == 0) {
        for (int b = threadIdx.x; b < NB; b += 256) gcursor[b] = 0u;
        if (threadIdx.x == 0)
            for (int k = 0; k < out_size; ++k) d_out[k] = 0.0f;
    }
    __syncthreads();

    int i = blockIdx.x * 256 + threadIdx.x;
    if (i >= N_NODES) return;

    const float2* p2 = (const float2*)pred;
    const float2* t2 = (const float2*)target;
    float2 pa = p2[3 * i], pb = p2[3 * i + 1], pc = p2[3 * i + 2];
    float2 ta = t2[3 * i], tb = t2[3 * i + 1], tc = t2[3 * i + 2];
    float pr[6] = {pa.x, pa.y, pb.x, pb.y, pc.x, pc.y};
    float tg[6] = {ta.x, ta.y, tb.x, tb.y, tc.x, tc.y};
    int mk[6];
    if (s_mask8) {   // 1-byte bool: 3 aligned u16 loads
        const uint16_t* mu = (const uint16_t*)mask;
        uint16_t m0 = mu[3 * i], m1 = mu[3 * i + 1], m2 = mu[3 * i + 2];
        mk[0] = m0 & 0xFF; mk[1] = m0 >> 8;
        mk[2] = m1 & 0xFF; mk[3] = m1 >> 8;
        mk[4] = m2 & 0xFF; mk[5] = m2 >> 8;
    } else {         // int32: 3 aligned int2 loads
        const int2* mi = (const int2*)mask;
        int2 m0 = mi[3 * i], m1 = mi[3 * i + 1], m2 = mi[3 * i + 2];
        mk[0] = m0.x; mk[1] = m0.y; mk[2] = m1.x;
        mk[3] = m1.y; mk[4] = m2.x; mk[5] = m2.y;
    }
    float tp[6];
    #pragma unroll
    for (int j = 0; j < 6; ++j) tp[j] = mk[j] ? pr[j] : tg[j];

    float s, c;
    sincosf(tp[1], &s, &c);                      // 100K sincos total (not 3.2M)
    u_tab[i]   = make_float2(tp[0] * c, tp[0] * s);        // vm * e^{i va}
    base_pq[i] = make_float2(tp[2] - tp[4], tp[3] - tp[5]);
    ovf[i] = 0ull;
}

// ---------------------------------------------------------------------------
// Kernel 2: bin. Per-block: LDS histogram of src buckets -> one global cursor
// reservation atomic per (block,bucket) -> write 16B records
// {v.re, v.im, local_id} grouped by bucket. v = (g - i b) * conj(u_dst).
// No per-edge global atomics (overflow fallback only).
// ---------------------------------------------------------------------------
__global__ __launch_bounds__(256)
void bin_kernel(const void* __restrict__ edge_index,
                const float2* __restrict__ edge_attr,
                const float2* __restrict__ u_tab,
                uint32_t* __restrict__ gcursor,
                float4* __restrict__ recs,
                unsigned long long* __restrict__ ovf,
                int k_cap) {
    __shared__ uint32_t s_nodeid[CHUNK];   // 40 KB: src node id cache
    __shared__ uint32_t s_cnt[NB];         // counts, then running offsets
    __shared__ uint32_t s_base[NB];
    __shared__ int s_i64;

    if (threadIdx.x < 64) {
        uint32_t w = ((const uint32_t*)edge_index)[threadIdx.x];
        bool nz = (threadIdx.x & 1) && (w != 0u);   // odd word nonzero -> int32
        unsigned long long m = __ballot(nz);
        if (threadIdx.x == 0) s_i64 = (m == 0ull) ? 1 : 0;
    }
    for (int b = threadIdx.x; b < NB; b += 256) s_cnt[b] = 0u;
    __syncthreads();
    const bool is64 = (s_i64 != 0);
    const int ebase = blockIdx.x * CHUNK;
    const int nE = min(CHUNK, N_EDGES - ebase);

    // pass 1: count buckets, cache node ids
    for (int j = threadIdx.x; j < nE; j += 256) {
        int e = ebase + j;
        uint32_t src = is64 ? (uint32_t)((const unsigned long long*)edge_index)[e]
                            : ((const uint32_t*)edge_index)[e];
        s_nodeid[j] = src;
        atomicAdd(&s_cnt[src >> SHIFT], 1u);
    }
    __syncthreads();
    // reserve contiguous per-bucket chunks (391 global atomics per block)
    for (int b = threadIdx.x; b < NB; b += 256) {
        uint32_t cnt = s_cnt[b];
        s_base[b] = cnt ? atomicAdd(&gcursor[b], cnt) : 0u;
        s_cnt[b] = 0u;                     // reuse as running offset
    }
    __syncthreads();
    // pass 2: compute v, write record
    for (int j = threadIdx.x; j < nE; j += 256) {
        int e = ebase + j;
        uint32_t dst = is64 ? (uint32_t)((const unsigned long long*)edge_index)[N_EDGES + e]
                            : ((const uint32_t*)edge_index)[N_EDGES + e];
        float2 gb = edge_attr[e];          // g, b
        float2 u  = u_tab[dst];            // conj taken in formula
        float vr = gb.x * u.x - gb.y * u.y;          // Re[(g-ib)conj(u)]
        float vi = -(gb.y * u.x + gb.x * u.y);       // Im[(g-ib)conj(u)]
        uint32_t nid = s_nodeid[j];
        uint32_t bk = nid >> SHIFT, lid = nid & (SPAN - 1);
        uint32_t r = atomicAdd(&s_cnt[bk], 1u);      // LDS
        uint32_t pos = s_base[bk] + r;
        if ((int)pos < k_cap) {
            float4 rc;
            rc.x = vr; rc.y = vi; rc.z = __uint_as_float(lid); rc.w = 0.0f;
            recs[(size_t)bk * k_cap + pos] = rc;
        } else {   // statistically never: exact u64 fixed-point fallback
            int pi = __float2int_rn(vr * FP_SCALE);
            int qi = __float2int_rn(vi * FP_SCALE);
            unsigned long long enc =
                ((unsigned long long)(long long)pi << 32) +
                (unsigned long long)(unsigned int)qi;
            atomicAdd(&ovf[nid], enc);
        }
    }
}

// ---------------------------------------------------------------------------
// Kernel 3: reduce. One block per bucket: LDS f32 accumulate its records,
// then per-node c = u*S, loss contribution, one f32 atomic per block.
// ---------------------------------------------------------------------------
__global__ __launch_bounds__(256)
void reduce_kernel(const float4* __restrict__ recs,
                   const uint32_t* __restrict__ gcursor,
                   const float2* __restrict__ u_tab,
                   const float2* __restrict__ base_pq,
                   const unsigned long long* __restrict__ ovf,
                   float* __restrict__ d_out, int k_cap) {
    __shared__ float2 s_acc[SPAN];
    __shared__ float s_part[4];
    s_acc[threadIdx.x] = make_float2(0.0f, 0.0f);
    __syncthreads();

    const int b = blockIdx.x;
    const int n = min((int)gcursor[b], k_cap);
    const float4* r = recs + (size_t)b * k_cap;
    for (int j = threadIdx.x; j < n; j += 256) {
        float4 rc = r[j];
        uint32_t lid = __float_as_uint(rc.z);
        atomicAdd(&s_acc[lid].x, rc.x);
        atomicAdd(&s_acc[lid].y, rc.y);
    }
    __syncthreads();

    float v = 0.0f;
    int node = b * SPAN + threadIdx.x;
    if (node < N_NODES) {
        float2 S = s_acc[threadIdx.x];
        unsigned long long u = ovf[node];
        if (u) {
            int qs = (int)(unsigned int)(u & 0xFFFFFFFFull);
            long long rem = (long long)(u - (unsigned long long)(long long)qs);
            int ps = (int)(rem >> 32);
            S.x += (float)ps * FP_INV;
            S.y += (float)qs * FP_INV;
        }
        float2 ui = u_tab[node];
        float2 bp = base_pq[node];
        float pc = ui.x * S.x - ui.y * S.y;   // Re(u*S)
        float qc = ui.x * S.y + ui.y * S.x;   // Im(u*S)
        float p = bp.x - pc, q = bp.y - qc;
        v = p * p + q * q;
    }
    #pragma unroll
    for (int off = 32; off > 0; off >>= 1) v += __shfl_down(v, off, 64);
    if ((threadIdx.x & 63) == 0) s_part[threadIdx.x >> 6] = v;
    __syncthreads();
    if (threadIdx.x == 0)
        atomicAdd(d_out, (s_part[0] + s_part[1] + s_part[2] + s_part[3]) *
                         (1.0f / (float)N_NODES));
}

// ---------------------------------------------------------------------------
extern "C" void kernel_launch(void* const* d_in, const int* in_sizes, int n_in,
                              void* d_out, int out_size, void* d_ws, size_t ws_size,
                              hipStream_t stream) {
    const float*  pred       = (const float*)d_in[0];
    const float*  target     = (const float*)d_in[1];
    const void*   edge_index = d_in[2];
    const float2* edge_attr  = (const float2*)d_in[3];
    const void*   mask       = d_in[4];
    float* out = (float*)d_out;

    char* ws = (char*)d_ws;
    float2*             u_tab   = (float2*)ws;                     // 800 KB
    float2*             base_pq = (float2*)(ws + 800000);          // 800 KB
    unsigned long long* ovf     = (unsigned long long*)(ws + 1600000); // 800 KB
    uint32_t*           gcursor = (uint32_t*)(ws + 2400000);       // 1.6 KB
    float4*             recs    = (float4*)(ws + 2404096);         // NB*k_cap*16

    long long avail = (long long)ws_size - 2404096;
    long long kc = (avail > 0) ? (avail / ((long long)NB * 16)) : 0;
    int k_cap = (int)((kc > K_MAX) ? K_MAX : kc);   // graceful degradation via ovf

    prep_kernel<<<(N_NODES + 255) / 256, 256, 0, stream>>>(
        pred, target, mask, u_tab, base_pq, ovf, gcursor, out, out_size);

    bin_kernel<<<NBLK_A, 256, 0, stream>>>(
        edge_index, edge_attr, u_tab, gcursor, recs, ovf, k_cap);

    reduce_kernel<<<NB, 256, 0, stream>>>(
        recs, gcursor, u_tab, base_pq, ovf, out, k_cap);
}

// Round 6
// 201.781 us; speedup vs baseline: 2.7738x; 1.1168x over previous
//
#include <hip/hip_runtime.h>
#include <cstdint>

#define N_NODES 100000
#define N_EDGES 3200000
#define SPAN    256                              // nodes per bucket
#define SHIFT   8
#define NB      ((N_NODES + SPAN - 1) / SPAN)    // 391 buckets
#define CHUNK   4096                             // edges per bin block
#define NITER   (CHUNK / 256)                    // 16
#define NBLK_A  ((N_EDGES + CHUNK - 1) / CHUNK)  // 782 blocks
#define K_MAX   12288                            // bucket cap (mean 8184, sigma~90)

// u64 fixed-point overflow fallback (proven exact in round 4)
#define FP_SCALE 4096.0f
#define FP_INV   (1.0f / 4096.0f)

// ---------------------------------------------------------------------------
// Kernel 1: per-node prep. Inline mask-dtype detect; u = vm*e^{i va};
// base = (pg-pd, qg-qd); zero ovf, gcursor, d_out.
// ---------------------------------------------------------------------------
__global__ __launch_bounds__(256)
void prep_kernel(const float* __restrict__ pred,
                 const float* __restrict__ target,
                 const void* __restrict__ mask,
                 float2* __restrict__ u_tab,
                 float2* __restrict__ base_pq,
                 unsigned long long* __restrict__ ovf,
                 uint32_t* __restrict__ gcursor,
                 float* __restrict__ d_out, int out_size) {
    __shared__ int s_mask8;
    if (threadIdx.x < 64) {
        uint32_t w = ((const uint32_t*)mask)[threadIdx.x];
        bool nz = (w & 0xFFFFFF00u) != 0u;           // any off-aligned byte set
        unsigned long long m = __ballot(nz);
        if (threadIdx.x == 0) s_mask8 = (m != 0ull) ? 1 : 0;
    }
    if (blockIdx.x == 0) {
        for (int b = threadIdx.x; b < NB; b += 256) gcursor[b] = 0u;
        if (threadIdx.x == 0)
            for (int k = 0; k < out_size; ++k) d_out[k] = 0.0f;
    }
    __syncthreads();

    int i = blockIdx.x * 256 + threadIdx.x;
    if (i >= N_NODES) return;

    const float2* p2 = (const float2*)pred;
    const float2* t2 = (const float2*)target;
    float2 pa = p2[3 * i], pb = p2[3 * i + 1], pc = p2[3 * i + 2];
    float2 ta = t2[3 * i], tb = t2[3 * i + 1], tc = t2[3 * i + 2];
    float pr[6] = {pa.x, pa.y, pb.x, pb.y, pc.x, pc.y};
    float tg[6] = {ta.x, ta.y, tb.x, tb.y, tc.x, tc.y};
    int mk[6];
    if (s_mask8) {   // 1-byte bool
        const uint16_t* mu = (const uint16_t*)mask;
        uint16_t m0 = mu[3 * i], m1 = mu[3 * i + 1], m2 = mu[3 * i + 2];
        mk[0] = m0 & 0xFF; mk[1] = m0 >> 8;
        mk[2] = m1 & 0xFF; mk[3] = m1 >> 8;
        mk[4] = m2 & 0xFF; mk[5] = m2 >> 8;
    } else {         // int32
        const int2* mi = (const int2*)mask;
        int2 m0 = mi[3 * i], m1 = mi[3 * i + 1], m2 = mi[3 * i + 2];
        mk[0] = m0.x; mk[1] = m0.y; mk[2] = m1.x;
        mk[3] = m1.y; mk[4] = m2.x; mk[5] = m2.y;
    }
    float tp[6];
    #pragma unroll
    for (int j = 0; j < 6; ++j) tp[j] = mk[j] ? pr[j] : tg[j];

    float s, c;
    sincosf(tp[1], &s, &c);
    u_tab[i]   = make_float2(tp[0] * c, tp[0] * s);
    base_pq[i] = make_float2(tp[2] - tp[4], tp[3] - tp[5]);
    ovf[i] = 0ull;
}

// ---------------------------------------------------------------------------
// Kernel 2: bin with LDS counting sort. Per 4096-edge block:
//  pass1 histogram (src cached in regs) -> exclusive scan -> per-bucket global
//  cursor reservation -> pass2 compute 8B record {vr|lid, vi}, place sorted in
//  LDS -> coalesced run writes (consecutive threads -> consecutive slots).
// ---------------------------------------------------------------------------
__global__ __launch_bounds__(256)
void bin_kernel(const void* __restrict__ edge_index,
                const float2* __restrict__ edge_attr,
                const float2* __restrict__ u_tab,
                uint32_t* __restrict__ gcursor,
                uint2* __restrict__ recs,
                unsigned long long* __restrict__ ovf,
                int k_cap) {
    __shared__ uint2 s_rec[CHUNK];         // 32 KB; first 4KB doubles as scan scratch
    __shared__ uint32_t s_cnt[NB];         // counts, then running ranks
    __shared__ uint32_t s_pref[NB + 1];    // exclusive prefix
    __shared__ uint32_t s_gbase[NB];       // reserved global bases
    __shared__ int s_i64;

    uint32_t* scanA = (uint32_t*)s_rec;    // 512 u32
    uint32_t* scanB = scanA + 512;         // 512 u32 (total 4KB < 32KB)

    const int tid = threadIdx.x;
    if (tid < 64) {
        uint32_t w = ((const uint32_t*)edge_index)[tid];
        bool nz = (tid & 1) && (w != 0u);  // odd word nonzero -> int32
        unsigned long long m = __ballot(nz);
        if (tid == 0) s_i64 = (m == 0ull) ? 1 : 0;
    }
    for (int b = tid; b < NB; b += 256) s_cnt[b] = 0u;
    __syncthreads();
    const bool is64 = (s_i64 != 0);
    const int ebase = blockIdx.x * CHUNK;
    const int nE = min(CHUNK, N_EDGES - ebase);

    // pass 1: histogram, cache src ids in registers
    uint32_t src_r[NITER];
    #pragma unroll
    for (int it = 0; it < NITER; ++it) {
        int j = it * 256 + tid;
        uint32_t s = 0u;
        if (j < nE) {
            int e = ebase + j;
            s = is64 ? (uint32_t)((const unsigned long long*)edge_index)[e]
                     : ((const uint32_t*)edge_index)[e];
            atomicAdd(&s_cnt[s >> SHIFT], 1u);
        }
        src_r[it] = s;
    }
    __syncthreads();

    // exclusive scan of s_cnt into s_pref (Hillis-Steele over 512, ping-pong)
    {
        scanA[tid]       = (tid < NB) ? s_cnt[tid] : 0u;
        scanA[tid + 256] = (tid + 256 < NB) ? s_cnt[tid + 256] : 0u;
        __syncthreads();
        uint32_t* sa = scanA; uint32_t* sb = scanB;
        for (int off = 1; off < 512; off <<= 1) {
            #pragma unroll
            for (int h = 0; h < 2; ++h) {
                int k = h * 256 + tid;
                uint32_t v = sa[k];
                if (k >= off) v += sa[k - off];
                sb[k] = v;
            }
            __syncthreads();
            uint32_t* t = sa; sa = sb; sb = t;
        }
        if (tid == 0) s_pref[0] = 0u;
        for (int b = tid; b < NB; b += 256) s_pref[b + 1] = sa[b];
        __syncthreads();
    }

    // reserve per-bucket global space; reset s_cnt as running rank
    for (int b = tid; b < NB; b += 256) {
        uint32_t cnt = s_pref[b + 1] - s_pref[b];
        s_gbase[b] = cnt ? atomicAdd(&gcursor[b], cnt) : 0u;
        s_cnt[b] = 0u;
    }
    __syncthreads();

    // pass 2: compute record, place bucket-sorted in LDS
    #pragma unroll
    for (int it = 0; it < NITER; ++it) {
        int j = it * 256 + tid;
        if (j < nE) {
            int e = ebase + j;
            uint32_t dst = is64
                ? (uint32_t)((const unsigned long long*)edge_index)[(size_t)N_EDGES + e]
                : ((const uint32_t*)edge_index)[(size_t)N_EDGES + e];
            float2 gb = edge_attr[e];
            float2 u  = u_tab[dst];
            float vr = gb.x * u.x - gb.y * u.y;        // Re[(g-ib)conj(u)]
            float vi = -(gb.y * u.x + gb.x * u.y);     // Im[(g-ib)conj(u)]
            uint32_t nid = src_r[it];
            uint32_t bk = nid >> SHIFT, lid = nid & (SPAN - 1);
            uint32_t r = atomicAdd(&s_cnt[bk], 1u);    // intra-block rank
            uint2 rc;
            rc.x = (__float_as_uint(vr) & ~0xFFu) | lid;  // lid in low mantissa
            rc.y = __float_as_uint(vi);
            s_rec[s_pref[bk] + r] = rc;
        }
    }
    __syncthreads();

    // write: consecutive threads -> consecutive sorted slots -> coalesced runs
    for (int slot = tid; slot < nE; slot += 256) {
        int lo = 0, hi = NB;                  // find bk: s_pref[bk]<=slot<s_pref[bk+1]
        while (hi - lo > 1) {
            int mid = (lo + hi) >> 1;
            if (s_pref[mid] <= (uint32_t)slot) lo = mid; else hi = mid;
        }
        int bk = lo;
        uint32_t pos = s_gbase[bk] + ((uint32_t)slot - s_pref[bk]);
        uint2 rc = s_rec[slot];
        if ((int)pos < k_cap) {
            recs[(size_t)bk * k_cap + pos] = rc;
        } else {   // statistically never: exact u64 fixed-point fallback
            float vr = __uint_as_float(rc.x & ~0xFFu);
            float vi = __uint_as_float(rc.y);
            uint32_t nid = ((uint32_t)bk << SHIFT) | (rc.x & 0xFFu);
            int pi = __float2int_rn(vr * FP_SCALE);
            int qi = __float2int_rn(vi * FP_SCALE);
            unsigned long long enc =
                ((unsigned long long)(long long)pi << 32) +
                (unsigned long long)(unsigned int)qi;
            atomicAdd(&ovf[nid], enc);
        }
    }
}

// ---------------------------------------------------------------------------
// Kernel 3: reduce. One 1024-thread block per bucket: contiguous record read,
// LDS f32 accumulate, per-node loss contribution, one f32 atomic per block.
// ---------------------------------------------------------------------------
__global__ __launch_bounds__(1024)
void reduce_kernel(const uint2* __restrict__ recs,
                   const uint32_t* __restrict__ gcursor,
                   const float2* __restrict__ u_tab,
                   const float2* __restrict__ base_pq,
                   const unsigned long long* __restrict__ ovf,
                   float* __restrict__ d_out, int k_cap) {
    __shared__ float2 s_acc[SPAN];
    __shared__ float s_part[16];
    if (threadIdx.x < SPAN) s_acc[threadIdx.x] = make_float2(0.0f, 0.0f);
    __syncthreads();

    const int b = blockIdx.x;
    const int n = min((int)gcursor[b], k_cap);
    const uint2* r = recs + (size_t)b * k_cap;
    for (int j = threadIdx.x; j < n; j += 1024) {
        uint2 rc = r[j];
        uint32_t lid = rc.x & 0xFFu;
        atomicAdd(&s_acc[lid].x, __uint_as_float(rc.x & ~0xFFu));
        atomicAdd(&s_acc[lid].y, __uint_as_float(rc.y));
    }
    __syncthreads();

    float v = 0.0f;
    int node = b * SPAN + (int)threadIdx.x;
    if (threadIdx.x < SPAN && node < N_NODES) {
        float2 S = s_acc[threadIdx.x];
        unsigned long long u = ovf[node];
        if (u) {
            int qs = (int)(unsigned int)(u & 0xFFFFFFFFull);
            long long rem = (long long)(u - (unsigned long long)(long long)qs);
            int ps = (int)(rem >> 32);
            S.x += (float)ps * FP_INV;
            S.y += (float)qs * FP_INV;
        }
        float2 ui = u_tab[node];
        float2 bp = base_pq[node];
        float pc = ui.x * S.x - ui.y * S.y;   // Re(u*S)
        float qc = ui.x * S.y + ui.y * S.x;   // Im(u*S)
        float p = bp.x - pc, q = bp.y - qc;
        v = p * p + q * q;
    }
    #pragma unroll
    for (int off = 32; off > 0; off >>= 1) v += __shfl_down(v, off, 64);
    if ((threadIdx.x & 63) == 0) s_part[threadIdx.x >> 6] = v;
    __syncthreads();
    if (threadIdx.x == 0) {
        float t = 0.0f;
        #pragma unroll
        for (int w = 0; w < 16; ++w) t += s_part[w];
        atomicAdd(d_out, t * (1.0f / (float)N_NODES));
    }
}

// ---------------------------------------------------------------------------
extern "C" void kernel_launch(void* const* d_in, const int* in_sizes, int n_in,
                              void* d_out, int out_size, void* d_ws, size_t ws_size,
                              hipStream_t stream) {
    const float*  pred       = (const float*)d_in[0];
    const float*  target     = (const float*)d_in[1];
    const void*   edge_index = d_in[2];
    const float2* edge_attr  = (const float2*)d_in[3];
    const void*   mask       = d_in[4];
    float* out = (float*)d_out;

    char* ws = (char*)d_ws;
    float2*             u_tab   = (float2*)ws;                         // 800 KB
    float2*             base_pq = (float2*)(ws + 800000);              // 800 KB
    unsigned long long* ovf     = (unsigned long long*)(ws + 1600000); // 800 KB
    uint32_t*           gcursor = (uint32_t*)(ws + 2400000);           // 1.6 KB
    uint2*              recs    = (uint2*)(ws + 2404096);              // NB*k_cap*8

    long long avail = (long long)ws_size - 2404096;
    long long kc = (avail > 0) ? (avail / ((long long)NB * 8)) : 0;
    int k_cap = (int)((kc > K_MAX) ? K_MAX : kc);   // graceful degradation via ovf

    prep_kernel<<<(N_NODES + 255) / 256, 256, 0, stream>>>(
        pred, target, mask, u_tab, base_pq, ovf, gcursor, out, out_size);

    bin_kernel<<<NBLK_A, 256, 0, stream>>>(
        edge_index, edge_attr, u_tab, gcursor, recs, ovf, k_cap);

    reduce_kernel<<<NB, 1024, 0, stream>>>(
        recs, gcursor, u_tab, base_pq, ovf, out, k_cap);
}

// Round 7
// 198.472 us; speedup vs baseline: 2.8201x; 1.0167x over previous
//
#include <hip/hip_runtime.h>
#include <cstdint>

#define N_NODES 100000
#define N_EDGES 3200000
#define SPAN    256                              // nodes per bucket
#define SHIFT   8
#define NB      ((N_NODES + SPAN - 1) / SPAN)    // 391 buckets
#define CHUNK   4096                             // edges per bin block
#define BTHREADS 512
#define NITER   (CHUNK / BTHREADS)               // 8
#define NBLK_A  ((N_EDGES + CHUNK - 1) / CHUNK)  // 782 blocks
#define K_MAX   12288                            // bucket cap (mean 8184, sigma~90)

// u64 fixed-point overflow fallback (proven exact in round 4)
#define FP_SCALE 4096.0f
#define FP_INV   (1.0f / 4096.0f)

// ---------------------------------------------------------------------------
// Kernel 1: per-node prep. Inline mask-dtype detect; u = vm*e^{i va};
// base = (pg-pd, qg-qd); zero ovf, gcursor, d_out.
// ---------------------------------------------------------------------------
__global__ __launch_bounds__(256)
void prep_kernel(const float* __restrict__ pred,
                 const float* __restrict__ target,
                 const void* __restrict__ mask,
                 float2* __restrict__ u_tab,
                 float2* __restrict__ base_pq,
                 unsigned long long* __restrict__ ovf,
                 uint32_t* __restrict__ gcursor,
                 float* __restrict__ d_out, int out_size) {
    __shared__ int s_mask8;
    if (threadIdx.x < 64) {
        uint32_t w = ((const uint32_t*)mask)[threadIdx.x];
        bool nz = (w & 0xFFFFFF00u) != 0u;           // any off-aligned byte set
        unsigned long long m = __ballot(nz);
        if (threadIdx.x == 0) s_mask8 = (m != 0ull) ? 1 : 0;
    }
    if (blockIdx.x == 0) {
        for (int b = threadIdx.x; b < NB; b += 256) gcursor[b] = 0u;
        if (threadIdx.x == 0)
            for (int k = 0; k < out_size; ++k) d_out[k] = 0.0f;
    }
    __syncthreads();

    int i = blockIdx.x * 256 + threadIdx.x;
    if (i >= N_NODES) return;

    const float2* p2 = (const float2*)pred;
    const float2* t2 = (const float2*)target;
    float2 pa = p2[3 * i], pb = p2[3 * i + 1], pc = p2[3 * i + 2];
    float2 ta = t2[3 * i], tb = t2[3 * i + 1], tc = t2[3 * i + 2];
    float pr[6] = {pa.x, pa.y, pb.x, pb.y, pc.x, pc.y};
    float tg[6] = {ta.x, ta.y, tb.x, tb.y, tc.x, tc.y};
    int mk[6];
    if (s_mask8) {   // 1-byte bool
        const uint16_t* mu = (const uint16_t*)mask;
        uint16_t m0 = mu[3 * i], m1 = mu[3 * i + 1], m2 = mu[3 * i + 2];
        mk[0] = m0 & 0xFF; mk[1] = m0 >> 8;
        mk[2] = m1 & 0xFF; mk[3] = m1 >> 8;
        mk[4] = m2 & 0xFF; mk[5] = m2 >> 8;
    } else {         // int32
        const int2* mi = (const int2*)mask;
        int2 m0 = mi[3 * i], m1 = mi[3 * i + 1], m2 = mi[3 * i + 2];
        mk[0] = m0.x; mk[1] = m0.y; mk[2] = m1.x;
        mk[3] = m1.y; mk[4] = m2.x; mk[5] = m2.y;
    }
    float tp[6];
    #pragma unroll
    for (int j = 0; j < 6; ++j) tp[j] = mk[j] ? pr[j] : tg[j];

    float s, c;
    sincosf(tp[1], &s, &c);
    u_tab[i]   = make_float2(tp[0] * c, tp[0] * s);
    base_pq[i] = make_float2(tp[2] - tp[4], tp[3] - tp[5]);
    ovf[i] = 0ull;
}

// ---------------------------------------------------------------------------
// Kernel 2: bin with LDS counting sort (512 threads, 8 waves).
// Record: rc.x = vr with low 8 mantissa bits = lid; rc.y = vi with low 9
// mantissa bits = bk  -> write pass needs NO search.
// Scan: wave64 shfl inclusive scan + 8 wave-sums, 2 barriers total.
// ---------------------------------------------------------------------------
__global__ __launch_bounds__(BTHREADS)
void bin_kernel(const void* __restrict__ edge_index,
                const float2* __restrict__ edge_attr,
                const float2* __restrict__ u_tab,
                uint32_t* __restrict__ gcursor,
                uint2* __restrict__ recs,
                unsigned long long* __restrict__ ovf,
                int k_cap) {
    __shared__ uint2 s_rec[CHUNK];         // 32 KB
    __shared__ uint32_t s_cnt[NB];         // counts, then running ranks
    __shared__ uint32_t s_pref[NB + 1];    // exclusive prefix
    __shared__ uint32_t s_gbase[NB];       // reserved global bases
    __shared__ uint32_t s_wsum[8], s_woff[8];
    __shared__ int s_i64;

    const int tid = threadIdx.x;
    const int lane = tid & 63, wid = tid >> 6;
    if (tid < 64) {
        uint32_t w = ((const uint32_t*)edge_index)[tid];
        bool nz = (tid & 1) && (w != 0u);  // odd word nonzero -> int32
        unsigned long long m = __ballot(nz);
        if (tid == 0) s_i64 = (m == 0ull) ? 1 : 0;
    }
    if (tid < NB) s_cnt[tid] = 0u;
    __syncthreads();
    const bool is64 = (s_i64 != 0);
    const int ebase = blockIdx.x * CHUNK;
    const int nE = min(CHUNK, N_EDGES - ebase);

    // pass 1: histogram, cache src ids in registers
    uint32_t src_r[NITER];
    #pragma unroll
    for (int it = 0; it < NITER; ++it) {
        int j = it * BTHREADS + tid;
        uint32_t s = 0u;
        if (j < nE) {
            int e = ebase + j;
            s = is64 ? (uint32_t)((const unsigned long long*)edge_index)[e]
                     : ((const uint32_t*)edge_index)[e];
            atomicAdd(&s_cnt[s >> SHIFT], 1u);
        }
        src_r[it] = s;
    }
    __syncthreads();

    // two-level shfl scan over 512 slots (NB=391 live)
    {
        uint32_t v0 = (tid < NB) ? s_cnt[tid] : 0u;
        uint32_t x = v0;
        #pragma unroll
        for (int off = 1; off < 64; off <<= 1) {
            uint32_t y = (uint32_t)__shfl_up((int)x, off, 64);
            if (lane >= off) x += y;
        }
        if (lane == 63) s_wsum[wid] = x;
        __syncthreads();
        if (tid < 8) {
            uint32_t w0 = s_wsum[tid];
            uint32_t xx = w0;
            #pragma unroll
            for (int off = 1; off < 8; off <<= 1) {
                uint32_t y = (uint32_t)__shfl_up((int)xx, off, 64);
                if (tid >= off) xx += y;
            }
            s_woff[tid] = xx - w0;         // exclusive wave offset
        }
        __syncthreads();
        uint32_t incl = x + s_woff[wid];
        if (tid < NB) s_pref[tid + 1] = incl;
        if (tid == 0) s_pref[0] = 0u;
        // reserve per-bucket global space; reset s_cnt as running rank
        if (tid < NB) {
            uint32_t excl = incl - v0;
            s_gbase[tid] = v0 ? atomicAdd(&gcursor[tid], v0) : 0u;
            s_cnt[tid] = 0u;
            (void)excl;
        }
        __syncthreads();
    }

    // pass 2: compute record, place bucket-sorted in LDS
    #pragma unroll
    for (int it = 0; it < NITER; ++it) {
        int j = it * BTHREADS + tid;
        if (j < nE) {
            int e = ebase + j;
            uint32_t dst = is64
                ? (uint32_t)((const unsigned long long*)edge_index)[(size_t)N_EDGES + e]
                : ((const uint32_t*)edge_index)[(size_t)N_EDGES + e];
            float2 gb = edge_attr[e];
            float2 u  = u_tab[dst];
            float vr = gb.x * u.x - gb.y * u.y;        // Re[(g-ib)conj(u)]
            float vi = -(gb.y * u.x + gb.x * u.y);     // Im[(g-ib)conj(u)]
            uint32_t nid = src_r[it];
            uint32_t bk = nid >> SHIFT, lid = nid & (SPAN - 1);
            uint32_t r = atomicAdd(&s_cnt[bk], 1u);    // intra-block rank
            uint2 rc;
            rc.x = (__float_as_uint(vr) & ~0xFFu) | lid;    // lid: 8 bits
            rc.y = (__float_as_uint(vi) & ~0x1FFu) | bk;    // bk: 9 bits
            s_rec[s_pref[bk] + r] = rc;
        }
    }
    __syncthreads();

    // write: consecutive threads -> consecutive sorted slots; bk from record
    for (int slot = tid; slot < nE; slot += BTHREADS) {
        uint2 rc = s_rec[slot];
        uint32_t bk = rc.y & 0x1FFu;
        uint32_t pos = s_gbase[bk] + ((uint32_t)slot - s_pref[bk]);
        if ((int)pos < k_cap) {
            recs[(size_t)bk * k_cap + pos] = rc;
        } else {   // statistically never: exact u64 fixed-point fallback
            float vr = __uint_as_float(rc.x & ~0xFFu);
            float vi = __uint_as_float(rc.y & ~0x1FFu);
            uint32_t nid = (bk << SHIFT) | (rc.x & 0xFFu);
            int pi = __float2int_rn(vr * FP_SCALE);
            int qi = __float2int_rn(vi * FP_SCALE);
            unsigned long long enc =
                ((unsigned long long)(long long)pi << 32) +
                (unsigned long long)(unsigned int)qi;
            atomicAdd(&ovf[nid], enc);
        }
    }
}

// ---------------------------------------------------------------------------
// Kernel 3: reduce. One 1024-thread block per bucket: contiguous record read,
// 4x replicated LDS accumulators (per 4-wave group) to cut atomic contention.
// ---------------------------------------------------------------------------
__global__ __launch_bounds__(1024)
void reduce_kernel(const uint2* __restrict__ recs,
                   const uint32_t* __restrict__ gcursor,
                   const float2* __restrict__ u_tab,
                   const float2* __restrict__ base_pq,
                   const unsigned long long* __restrict__ ovf,
                   float* __restrict__ d_out, int k_cap) {
    __shared__ float2 s_acc[4][SPAN];      // 8 KB
    __shared__ float s_part[16];
    if (threadIdx.x < SPAN) {
        #pragma unroll
        for (int r = 0; r < 4; ++r) s_acc[r][threadIdx.x] = make_float2(0.0f, 0.0f);
    }
    __syncthreads();

    const int b = blockIdx.x;
    const int n = min((int)gcursor[b], k_cap);
    const int rep = (threadIdx.x >> 6) & 3;          // wave id mod 4
    const uint2* r = recs + (size_t)b * k_cap;
    for (int j = threadIdx.x; j < n; j += 1024) {
        uint2 rc = r[j];
        uint32_t lid = rc.x & 0xFFu;
        atomicAdd(&s_acc[rep][lid].x, __uint_as_float(rc.x & ~0xFFu));
        atomicAdd(&s_acc[rep][lid].y, __uint_as_float(rc.y & ~0x1FFu));
    }
    __syncthreads();

    float v = 0.0f;
    int node = b * SPAN + (int)threadIdx.x;
    if (threadIdx.x < SPAN && node < N_NODES) {
        float2 S = make_float2(0.0f, 0.0f);
        #pragma unroll
        for (int rr = 0; rr < 4; ++rr) {
            float2 t = s_acc[rr][threadIdx.x];
            S.x += t.x; S.y += t.y;
        }
        unsigned long long u = ovf[node];
        if (u) {
            int qs = (int)(unsigned int)(u & 0xFFFFFFFFull);
            long long rem = (long long)(u - (unsigned long long)(long long)qs);
            int ps = (int)(rem >> 32);
            S.x += (float)ps * FP_INV;
            S.y += (float)qs * FP_INV;
        }
        float2 ui = u_tab[node];
        float2 bp = base_pq[node];
        float pc = ui.x * S.x - ui.y * S.y;   // Re(u*S)
        float qc = ui.x * S.y + ui.y * S.x;   // Im(u*S)
        float p = bp.x - pc, q = bp.y - qc;
        v = p * p + q * q;
    }
    #pragma unroll
    for (int off = 32; off > 0; off >>= 1) v += __shfl_down(v, off, 64);
    if ((threadIdx.x & 63) == 0) s_part[threadIdx.x >> 6] = v;
    __syncthreads();
    if (threadIdx.x == 0) {
        float t = 0.0f;
        #pragma unroll
        for (int w = 0; w < 16; ++w) t += s_part[w];
        atomicAdd(d_out, t * (1.0f / (float)N_NODES));
    }
}

// ---------------------------------------------------------------------------
extern "C" void kernel_launch(void* const* d_in, const int* in_sizes, int n_in,
                              void* d_out, int out_size, void* d_ws, size_t ws_size,
                              hipStream_t stream) {
    const float*  pred       = (const float*)d_in[0];
    const float*  target     = (const float*)d_in[1];
    const void*   edge_index = d_in[2];
    const float2* edge_attr  = (const float2*)d_in[3];
    const void*   mask       = d_in[4];
    float* out = (float*)d_out;

    char* ws = (char*)d_ws;
    float2*             u_tab   = (float2*)ws;                         // 800 KB
    float2*             base_pq = (float2*)(ws + 800000);              // 800 KB
    unsigned long long* ovf     = (unsigned long long*)(ws + 1600000); // 800 KB
    uint32_t*           gcursor = (uint32_t*)(ws + 2400000);           // 1.6 KB
    uint2*              recs    = (uint2*)(ws + 2404096);              // NB*k_cap*8

    long long avail = (long long)ws_size - 2404096;
    long long kc = (avail > 0) ? (avail / ((long long)NB * 8)) : 0;
    int k_cap = (int)((kc > K_MAX) ? K_MAX : kc);   // graceful degradation via ovf

    prep_kernel<<<(N_NODES + 255) / 256, 256, 0, stream>>>(
        pred, target, mask, u_tab, base_pq, ovf, gcursor, out, out_size);

    bin_kernel<<<NBLK_A, BTHREADS, 0, stream>>>(
        edge_index, edge_attr, u_tab, gcursor, recs, ovf, k_cap);

    reduce_kernel<<<NB, 1024, 0, stream>>>(
        recs, gcursor, u_tab, base_pq, ovf, out, k_cap);
}

// Round 8
// 173.180 us; speedup vs baseline: 3.2319x; 1.1460x over previous
//
#include <hip/hip_runtime.h>
#include <cstdint>

#define N_NODES 100000
#define N_EDGES 3200000
#define SPAN    256                              // nodes per bucket
#define SHIFT   8
#define NB      ((N_NODES + SPAN - 1) / SPAN)    // 391 buckets
#define CHUNK   4096                             // edges per bin block
#define BTH     512
#define NITER   (CHUNK / BTH)                    // 8
#define NBLK    ((N_EDGES + CHUNK - 1) / CHUNK)  // 782 blocks
#define PREF_W  (NB + 1)                         // 392

// ---------------------------------------------------------------------------
// Kernel 1: per-node prep. Inline mask-dtype detect; u = vm*e^{i va};
// base = (pg-pd, qg-qd); zero d_out.
// ---------------------------------------------------------------------------
__global__ __launch_bounds__(256)
void prep_kernel(const float* __restrict__ pred,
                 const float* __restrict__ target,
                 const void* __restrict__ mask,
                 float2* __restrict__ u_tab,
                 float2* __restrict__ base_pq,
                 float* __restrict__ d_out, int out_size) {
    __shared__ int s_mask8;
    if (threadIdx.x < 64) {
        uint32_t w = ((const uint32_t*)mask)[threadIdx.x];
        bool nz = (w & 0xFFFFFF00u) != 0u;           // any off-aligned byte set
        unsigned long long m = __ballot(nz);
        if (threadIdx.x == 0) s_mask8 = (m != 0ull) ? 1 : 0;
    }
    if (blockIdx.x == 0 && threadIdx.x == 0)
        for (int k = 0; k < out_size; ++k) d_out[k] = 0.0f;
    __syncthreads();

    int i = blockIdx.x * 256 + threadIdx.x;
    if (i >= N_NODES) return;

    const float2* p2 = (const float2*)pred;
    const float2* t2 = (const float2*)target;
    float2 pa = p2[3 * i], pb = p2[3 * i + 1], pc = p2[3 * i + 2];
    float2 ta = t2[3 * i], tb = t2[3 * i + 1], tc = t2[3 * i + 2];
    float pr[6] = {pa.x, pa.y, pb.x, pb.y, pc.x, pc.y};
    float tg[6] = {ta.x, ta.y, tb.x, tb.y, tc.x, tc.y};
    int mk[6];
    if (s_mask8) {   // 1-byte bool
        const uint16_t* mu = (const uint16_t*)mask;
        uint16_t m0 = mu[3 * i], m1 = mu[3 * i + 1], m2 = mu[3 * i + 2];
        mk[0] = m0 & 0xFF; mk[1] = m0 >> 8;
        mk[2] = m1 & 0xFF; mk[3] = m1 >> 8;
        mk[4] = m2 & 0xFF; mk[5] = m2 >> 8;
    } else {         // int32
        const int2* mi = (const int2*)mask;
        int2 m0 = mi[3 * i], m1 = mi[3 * i + 1], m2 = mi[3 * i + 2];
        mk[0] = m0.x; mk[1] = m0.y; mk[2] = m1.x;
        mk[3] = m1.y; mk[4] = m2.x; mk[5] = m2.y;
    }
    float tp[6];
    #pragma unroll
    for (int j = 0; j < 6; ++j) tp[j] = mk[j] ? pr[j] : tg[j];

    float s, c;
    sincosf(tp[1], &s, &c);
    u_tab[i]   = make_float2(tp[0] * c, tp[0] * s);
    base_pq[i] = make_float2(tp[2] - tp[4], tp[3] - tp[5]);
}

// ---------------------------------------------------------------------------
// Kernel 2: bin. Per 4096-edge block: histogram -> shfl scan -> LDS counting
// sort -> STREAMING arena write (deterministic, zero global atomics) + prefix
// row. Record: rc.x = vr with low 8 mantissa bits = lid; rc.y = vi (exact).
// ---------------------------------------------------------------------------
__global__ __launch_bounds__(BTH)
void bin_kernel(const void* __restrict__ edge_index,
                const float2* __restrict__ edge_attr,
                const float2* __restrict__ u_tab,
                uint2* __restrict__ recs,          // [NBLK][CHUNK]
                uint32_t* __restrict__ pref) {     // [NBLK][PREF_W]
    __shared__ uint2 s_rec[CHUNK];         // 32 KB
    __shared__ uint32_t s_cnt[NB];         // counts, then running ranks
    __shared__ uint32_t s_pref[PREF_W];    // exclusive prefix
    __shared__ uint32_t s_wsum[8], s_woff[8];
    __shared__ int s_i64;

    const int tid = threadIdx.x;
    const int lane = tid & 63, wid = tid >> 6;
    if (tid < 64) {
        uint32_t w = ((const uint32_t*)edge_index)[tid];
        bool nz = (tid & 1) && (w != 0u);  // odd word nonzero -> int32
        unsigned long long m = __ballot(nz);
        if (tid == 0) s_i64 = (m == 0ull) ? 1 : 0;
    }
    if (tid < NB) s_cnt[tid] = 0u;
    __syncthreads();
    const bool is64 = (s_i64 != 0);
    const int ebase = blockIdx.x * CHUNK;
    const int nE = min(CHUNK, N_EDGES - ebase);

    // pass 1: histogram, cache src ids in registers
    uint32_t src_r[NITER];
    #pragma unroll
    for (int it = 0; it < NITER; ++it) {
        int j = it * BTH + tid;
        uint32_t s = 0u;
        if (j < nE) {
            int e = ebase + j;
            s = is64 ? (uint32_t)((const unsigned long long*)edge_index)[e]
                     : ((const uint32_t*)edge_index)[e];
            atomicAdd(&s_cnt[s >> SHIFT], 1u);
        }
        src_r[it] = s;
    }
    __syncthreads();

    // two-level shfl scan over 512 slots (NB=391 live)
    {
        uint32_t v0 = (tid < NB) ? s_cnt[tid] : 0u;
        uint32_t x = v0;
        #pragma unroll
        for (int off = 1; off < 64; off <<= 1) {
            uint32_t y = (uint32_t)__shfl_up((int)x, off, 64);
            if (lane >= off) x += y;
        }
        if (lane == 63) s_wsum[wid] = x;
        __syncthreads();
        if (tid < 8) {
            uint32_t w0 = s_wsum[tid];
            uint32_t xx = w0;
            #pragma unroll
            for (int off = 1; off < 8; off <<= 1) {
                uint32_t y = (uint32_t)__shfl_up((int)xx, off, 64);
                if (tid >= off) xx += y;
            }
            s_woff[tid] = xx - w0;         // exclusive wave offset
        }
        __syncthreads();
        uint32_t incl = x + s_woff[wid];
        if (tid < NB) s_pref[tid + 1] = incl;
        if (tid == 0) s_pref[0] = 0u;
        if (tid < NB) s_cnt[tid] = 0u;     // reuse as running rank
        __syncthreads();
    }

    // pass 2: compute record, place bucket-sorted in LDS
    #pragma unroll
    for (int it = 0; it < NITER; ++it) {
        int j = it * BTH + tid;
        if (j < nE) {
            int e = ebase + j;
            uint32_t dst = is64
                ? (uint32_t)((const unsigned long long*)edge_index)[(size_t)N_EDGES + e]
                : ((const uint32_t*)edge_index)[(size_t)N_EDGES + e];
            float2 gb = edge_attr[e];
            float2 u  = u_tab[dst];
            float vr = gb.x * u.x - gb.y * u.y;        // Re[(g-ib)conj(u)]
            float vi = -(gb.y * u.x + gb.x * u.y);     // Im[(g-ib)conj(u)]
            uint32_t nid = src_r[it];
            uint32_t bk = nid >> SHIFT, lid = nid & (SPAN - 1);
            uint32_t r = atomicAdd(&s_cnt[bk], 1u);    // intra-block rank
            uint2 rc;
            rc.x = (__float_as_uint(vr) & ~0xFFu) | lid;    // lid: 8 bits
            rc.y = __float_as_uint(vi);                     // exact
            s_rec[s_pref[bk] + r] = rc;
        }
    }
    __syncthreads();

    // streaming arena write: fully coalesced uint4 copy (nE is even)
    {
        const uint4* s4 = (const uint4*)s_rec;
        uint4* a4 = (uint4*)(recs + (size_t)blockIdx.x * CHUNK);
        for (int k = tid; k < nE / 2; k += BTH) a4[k] = s4[k];
        if ((nE & 1) && tid == 0)
            recs[(size_t)blockIdx.x * CHUNK + nE - 1] = s_rec[nE - 1];
    }
    // prefix row write (coalesced)
    for (int b = tid; b < PREF_W; b += BTH)
        pref[(size_t)blockIdx.x * PREF_W + b] = s_pref[b];
}

// ---------------------------------------------------------------------------
// Kernel 3: reduce. One 1024-thread block per bucket b: thread t processes
// producer-block t's run [pref[t][b], pref[t][b+1]) — per-thread contiguous
// reads, LDS f32 accumulate (4 replicas), then loss contribution.
// ---------------------------------------------------------------------------
__global__ __launch_bounds__(1024)
void reduce_kernel(const uint2* __restrict__ recs,
                   const uint32_t* __restrict__ pref,
                   const float2* __restrict__ u_tab,
                   const float2* __restrict__ base_pq,
                   float* __restrict__ d_out) {
    __shared__ float2 s_acc[4][SPAN];      // 8 KB
    __shared__ float s_part[16];
    if (threadIdx.x < SPAN) {
        #pragma unroll
        for (int r = 0; r < 4; ++r) s_acc[r][threadIdx.x] = make_float2(0.0f, 0.0f);
    }
    __syncthreads();

    const int b = blockIdx.x;
    const int rep = (threadIdx.x >> 6) & 3;
    if (threadIdx.x < NBLK) {
        const uint32_t* prow = pref + (size_t)threadIdx.x * PREF_W;
        uint32_t s = prow[b], e = prow[b + 1];
        const uint2* arena = recs + (size_t)threadIdx.x * CHUNK;
        for (uint32_t j = s; j < e; ++j) {
            uint2 rc = arena[j];
            uint32_t lid = rc.x & 0xFFu;
            atomicAdd(&s_acc[rep][lid].x, __uint_as_float(rc.x & ~0xFFu));
            atomicAdd(&s_acc[rep][lid].y, __uint_as_float(rc.y));
        }
    }
    __syncthreads();

    float v = 0.0f;
    int node = b * SPAN + (int)threadIdx.x;
    if (threadIdx.x < SPAN && node < N_NODES) {
        float2 S = make_float2(0.0f, 0.0f);
        #pragma unroll
        for (int rr = 0; rr < 4; ++rr) {
            float2 t = s_acc[rr][threadIdx.x];
            S.x += t.x; S.y += t.y;
        }
        float2 ui = u_tab[node];
        float2 bp = base_pq[node];
        float pc = ui.x * S.x - ui.y * S.y;   // Re(u*S)
        float qc = ui.x * S.y + ui.y * S.x;   // Im(u*S)
        float p = bp.x - pc, q = bp.y - qc;
        v = p * p + q * q;
    }
    #pragma unroll
    for (int off = 32; off > 0; off >>= 1) v += __shfl_down(v, off, 64);
    if ((threadIdx.x & 63) == 0) s_part[threadIdx.x >> 6] = v;
    __syncthreads();
    if (threadIdx.x == 0) {
        float t = 0.0f;
        #pragma unroll
        for (int w = 0; w < 16; ++w) t += s_part[w];
        atomicAdd(d_out, t * (1.0f / (float)N_NODES));
    }
}

// ---------------------------------------------------------------------------
extern "C" void kernel_launch(void* const* d_in, const int* in_sizes, int n_in,
                              void* d_out, int out_size, void* d_ws, size_t ws_size,
                              hipStream_t stream) {
    const float*  pred       = (const float*)d_in[0];
    const float*  target     = (const float*)d_in[1];
    const void*   edge_index = d_in[2];
    const float2* edge_attr  = (const float2*)d_in[3];
    const void*   mask       = d_in[4];
    float* out = (float*)d_out;

    char* ws = (char*)d_ws;
    float2*   u_tab   = (float2*)ws;                      // 800,000 B
    float2*   base_pq = (float2*)(ws + 800000);           // 800,000 B
    uint32_t* pref    = (uint32_t*)(ws + 1600000);        // 782*392*4 = 1,226,176 B
    uint2*    recs    = (uint2*)(ws + 2826176);           // 782*4096*8 = 25,624,576 B
                                                          // total ~28.5 MB

    prep_kernel<<<(N_NODES + 255) / 256, 256, 0, stream>>>(
        pred, target, mask, u_tab, base_pq, out, out_size);

    bin_kernel<<<NBLK, BTH, 0, stream>>>(
        edge_index, edge_attr, u_tab, recs, pref);

    reduce_kernel<<<NB, 1024, 0, stream>>>(
        recs, pref, u_tab, base_pq, out);
}